// Round 3
// baseline (46699.524 us; speedup 1.0000x reference)
//
#include <hip/hip_runtime.h>
#include <stdint.h>

#define NB    256   // batch / segments
#define CIN   128   // input channels
#define HID   256   // hidden
#define TST   256   // only first 256 timesteps matter for the output
#define NCLS  400

#define GRPS  32    // batch groups
#define MEMB  8     // blocks per group (hidden-slice members)
#define BPG   8     // batches per group
#define RPB   128   // gate-rows per block (4 gates x 32 hid)
#define HPB   32    // hidden units per block
#define TPB   512   // threads per block
#define KQ    4     // K-quarters
#define KPT   96    // weight floats per thread (384/KQ) -- fits VGPRs w/o spill
#define SPD   12    // s_part padded row stride (floats)
#define SGD   10    // s_gate padded row stride (floats)

// ---- workspace layout (bytes) ----
#define WS_SUMS   0u                       // 256*128*4   = 131072
#define WS_HBUF   131072u                  // 2*256*256*4 = 524288  (double-buffered h)
#define WS_C0     655360u                  // 256*256*4   = 262144
#define WS_CTRS   917504u                  // 32*4 group barrier counters
#define WS_PP     1048576u                 // 256*32*8*32*4 = 8388608 masked partial sums

__device__ __forceinline__ float sigm(float v) { return 1.0f / (1.0f + __expf(-v)); }
__device__ __forceinline__ float tanh_(float v) {
  v = fminf(fmaxf(v, -15.0f), 15.0f);
  const float e = __expf(2.0f * v);
  return (e - 1.0f) / (e + 1.0f);
}

// ---------------- segment sums (the "input_means" that are really sums) ----------------
__global__ void k_segsum(const float* __restrict__ x, const int* __restrict__ lens,
                         float* __restrict__ sums) {
  const int b = blockIdx.x, t = threadIdx.x;
  __shared__ int   s_l[NB];
  __shared__ int   s_red[256];
  __shared__ float s_f[CIN];
  s_l[t] = lens[t];
  __syncthreads();
  int part = 0;
  for (int i = t; i < b; i += 256) part += s_l[i];
  s_red[t] = part; __syncthreads();
  for (int k = 128; k > 0; k >>= 1) { if (t < k) s_red[t] += s_red[t + k]; __syncthreads(); }
  const int off = s_red[0];
  const int len = s_l[b];
  const int c = t & 127, half = t >> 7;
  float a = 0.f;
  for (int r = half; r < len; r += 2) a += x[(size_t)(off + r) * CIN + c];
  if (half) s_f[c] = a;
  __syncthreads();
  if (!half) sums[b * CIN + c] = a + s_f[c];
}

// ---------------- h0 = relu(sums@W1h^T)@W2h^T ; c0 likewise ----------------
__global__ void k_init(const float* __restrict__ sums,
                       const float* __restrict__ w1h, const float* __restrict__ w2h,
                       const float* __restrict__ w1c, const float* __restrict__ w2c,
                       float* __restrict__ hbuf, float* __restrict__ c0) {
  const int b = blockIdx.x, t = threadIdx.x;
  __shared__ float s_in[CIN], s_h[CIN], s_c[CIN];
  if (t < CIN) s_in[t] = sums[b * CIN + t];
  __syncthreads();
  {
    const int j = t & 127;
    const float* w = (t < CIN ? w1h : w1c) + j * CIN;
    float a = 0.f;
    #pragma unroll 8
    for (int k = 0; k < CIN; k++) a += s_in[k] * w[k];
    a = fmaxf(a, 0.f);
    if (t < CIN) s_h[j] = a; else s_c[j] = a;
  }
  __syncthreads();
  float ah = 0.f, ac = 0.f;
  const float* wh = w2h + t * CIN;
  const float* wc = w2c + t * CIN;
  #pragma unroll 8
  for (int k = 0; k < CIN; k++) { ah += s_h[k] * wh[k]; ac += s_c[k] * wc[k]; }
  hbuf[b * HID + t] = ah;   // buffer 0 = h_0
  c0[b * HID + t]   = ac;
}

// ---------------- persistent LSTM recurrence ----------------
// 256 blocks = 32 batch-groups (8 batches) x 8 members (32 hid = 128 gate rows).
// 512 threads: thread = (gate-row r, K-quarter kq) -> only 96 weight floats in VGPRs.
// (Rounds 1-2: 384/192 floats/thread hit the 256-VGPR cap -> scratch spill -> 10 GB
//  HBM refetch per dispatch. 96 + ~60 overhead regs leaves the allocator slack.)
__launch_bounds__(TPB, 2)
__global__ void k_lstm(const float* __restrict__ x, const int* __restrict__ lens,
                       const float* __restrict__ Wih, const float* __restrict__ Whh,
                       const float* __restrict__ bih, const float* __restrict__ bhh,
                       const float* __restrict__ c0,
                       float* __restrict__ hbuf, float* __restrict__ pp,
                       int* __restrict__ ctrs) {
  const int p    = blockIdx.x;
  const int m    = p >> 5;            // member 0..7 (hidden slice)
  const int grp  = p & 31;            // batch group 0..31 (members at stride 32 -> same XCD)
  const int bat0 = grp * BPG;
  const int hid0 = m * HPB;

  const int t  = threadIdx.x;
  const int r  = t & 127;             // local gate-row 0..127
  const int kq = t >> 7;              // K-quarter 0..3 (wave-uniform)
  const int gidx = r >> 5, j = r & 31;
  const int row = gidx * HID + hid0 + j;   // global gate row 0..1023

  const int j2 = t & 31, b2 = (t >> 5) & 7;     // update role (t<256)
  const int ch = t & 127, bp0 = (t >> 7) * 2;   // x staging role (2 batches each)

  __shared__ float s_hx[(CIN + HID) * BPG];     // [384 k][8 b] = 12 KB
  __shared__ float s_part[KQ * RPB * SPD];      // 24 KB quarter partials (padded)
  __shared__ float s_gate[RPB * SGD];           // 5 KB (padded)
  __shared__ float s_red[256];
  __shared__ int   s_lens[NB];
  __shared__ int   s_off[BPG], s_len[BPG];

  if (t < NB) s_lens[t] = lens[t];
  __syncthreads();
  if (t < BPG) {
    int off = 0;
    for (int k = 0; k < bat0 + t; k++) off += s_lens[k];
    s_off[t] = off;
    s_len[t] = s_lens[bat0 + t];
  }
  __syncthreads();

  // ---- persistent weights: 96 fp32 in VGPRs (static indices after unroll) ----
  float w[KPT];
  {
    const int k0 = kq * KPT;
    #pragma unroll
    for (int q = 0; q < KPT / 4; q++) {
      const int k = k0 + q * 4;
      float4 v;
      if (k < CIN) v = *(const float4*)(Wih + (size_t)row * CIN + k);
      else         v = *(const float4*)(Whh + (size_t)row * HID + (k - CIN));
      w[q*4+0] = v.x; w[q*4+1] = v.y; w[q*4+2] = v.z; w[q*4+3] = v.w;
    }
  }
  const float bias = (kq == 0) ? (bih[row] + bhh[row]) : 0.f;

  float c_reg = (t < 256) ? c0[(size_t)(bat0 + b2) * HID + hid0 + j2] : 0.f;

  float xp0, xp1;
  auto prefx = [&](int s) {
    xp0 = (s < s_len[bp0 + 0]) ? x[(size_t)(s_off[bp0 + 0] + s) * CIN + ch] : 0.f;
    xp1 = (s < s_len[bp0 + 1]) ? x[(size_t)(s_off[bp0 + 1] + s) * CIN + ch] : 0.f;
  };
  auto stage = [&](int s) {
    *(float2*)&s_hx[ch * BPG + bp0] = make_float2(xp0, xp1);
    const int k = t & 255, bq = t >> 8;          // h staging: (hidden k, batch-quad)
    const float* hb = hbuf + (size_t)(s & 1) * NB * HID + k;
    float4 hv;
    hv.x = hb[(size_t)(bat0 + bq * 4 + 0) * HID];
    hv.y = hb[(size_t)(bat0 + bq * 4 + 1) * HID];
    hv.z = hb[(size_t)(bat0 + bq * 4 + 2) * HID];
    hv.w = hb[(size_t)(bat0 + bq * 4 + 3) * HID];
    *(float4*)&s_hx[(CIN + k) * BPG + bq * 4] = hv;
  };

  prefx(0);
  stage(0);
  __syncthreads();

  for (int s = 0; s < TST; s++) {
    // ---- gate quarter-partials: 96 K x 8 batches, hx rows are wave-uniform broadcasts ----
    float a0 = bias, a1 = bias, a2 = bias, a3 = bias;
    float a4 = bias, a5 = bias, a6 = bias, a7 = bias;
    const float4* hx4 = (const float4*)s_hx + (size_t)kq * KPT * 2;
    #pragma unroll
    for (int k = 0; k < KPT; k++) {
      const float4 lo = hx4[2 * k + 0];
      const float4 hi = hx4[2 * k + 1];
      const float ww = w[k];
      a0 = fmaf(ww, lo.x, a0); a1 = fmaf(ww, lo.y, a1);
      a2 = fmaf(ww, lo.z, a2); a3 = fmaf(ww, lo.w, a3);
      a4 = fmaf(ww, hi.x, a4); a5 = fmaf(ww, hi.y, a5);
      a6 = fmaf(ww, hi.z, a6); a7 = fmaf(ww, hi.w, a7);
    }
    if (s < TST - 1) prefx(s + 1);   // x loads drain during reduce/update/barrier

    {
      float* sp = s_part + (size_t)(kq * RPB + r) * SPD;
      *(float4*)(sp + 0) = make_float4(a0, a1, a2, a3);
      *(float4*)(sp + 4) = make_float4(a4, a5, a6, a7);
    }
    __syncthreads();

    // ---- quarter reduction: thread = (row rr, batch-pair bh) ----
    {
      const int rr = t & 127, bh = t >> 7;
      float g0 = 0.f, g1 = 0.f;
      #pragma unroll
      for (int q = 0; q < KQ; q++) {
        const float* sp = s_part + (size_t)(q * RPB + rr) * SPD + bh * 2;
        g0 += sp[0]; g1 += sp[1];
      }
      *(float2*)&s_gate[rr * SGD + bh * 2] = make_float2(g0, g1);
    }
    __syncthreads();

    // ---- LSTM update for (hidden j2, batch b2): threads 0..255 ----
    if (t < 256) {
      const float vi = s_gate[(0 * HPB + j2) * SGD + b2];
      const float vf = s_gate[(1 * HPB + j2) * SGD + b2];
      const float vg = s_gate[(2 * HPB + j2) * SGD + b2];
      const float vo = s_gate[(3 * HPB + j2) * SGD + b2];
      c_reg = fmaf(sigm(vf), c_reg, sigm(vi) * tanh_(vg));
      const float h = sigm(vo) * tanh_(c_reg);
      hbuf[(size_t)((s + 1) & 1) * NB * HID + (size_t)(bat0 + b2) * HID + hid0 + j2] = h;
      s_red[b2 * HPB + j2] = (bat0 + b2 < s_lens[s]) ? h : 0.f;
    }
    __syncthreads();

    // masked partial for output row s (overlaps barrier spin below)
    if (t >= 256 && t < 256 + HPB) {
      const int jl = t - 256;
      float ps = 0.f;
      #pragma unroll
      for (int b = 0; b < BPG; b++) ps += s_red[b * HPB + jl];
      pp[(((size_t)s * GRPS + grp) * MEMB + m) * HPB + jl] = ps;
    }

    if (s == TST - 1) break;

    // ---- 8-block group barrier: release arrive, relaxed spin + sleep, one acquire ----
    if (t == 0) {
      __hip_atomic_fetch_add(ctrs + grp, 1, __ATOMIC_RELEASE, __HIP_MEMORY_SCOPE_AGENT);
      const int target = MEMB * (s + 1);
      while (__hip_atomic_load(ctrs + grp, __ATOMIC_RELAXED, __HIP_MEMORY_SCOPE_AGENT) < target)
        __builtin_amdgcn_s_sleep(2);
      (void)__hip_atomic_load(ctrs + grp, __ATOMIC_ACQUIRE, __HIP_MEMORY_SCOPE_AGENT);
    }
    __syncthreads();
    stage(s + 1);
    __syncthreads();
  }
}

// ---------------- masked batch-mean + FC ----------------
__global__ void k_out(const float* __restrict__ pp, const int* __restrict__ lens,
                      const float* __restrict__ fcW, const float* __restrict__ fcb,
                      float* __restrict__ out) {
  const int i = blockIdx.x, t = threadIdx.x;
  __shared__ float s_fc[HID];
  const int cnt = min(lens[i], NB);
  const int m = t >> 5, jl = t & 31;             // hid = t
  float a = 0.f;
  const float* base = pp + ((size_t)i * GRPS * MEMB + m) * HPB + jl;
  #pragma unroll 4
  for (int g = 0; g < GRPS; g++) a += base[(size_t)g * MEMB * HPB];
  s_fc[t] = a / (float)cnt;
  __syncthreads();
  for (int n = t; n < NCLS; n += 256) {
    float acc = fcb[n];
    const float4* w4 = (const float4*)(fcW + (size_t)n * HID);
    #pragma unroll 8
    for (int k4 = 0; k4 < HID / 4; k4++) {
      const float4 w = w4[k4];
      acc = fmaf(s_fc[4*k4+0], w.x, acc);
      acc = fmaf(s_fc[4*k4+1], w.y, acc);
      acc = fmaf(s_fc[4*k4+2], w.z, acc);
      acc = fmaf(s_fc[4*k4+3], w.w, acc);
    }
    out[(size_t)i * NCLS + n] = acc;
  }
}

extern "C" void kernel_launch(void* const* d_in, const int* in_sizes, int n_in,
                              void* d_out, int out_size, void* d_ws, size_t ws_size,
                              hipStream_t stream) {
  const float* x    = (const float*)d_in[0];
  const int*   lens = (const int*)  d_in[1];
  const float* Wih  = (const float*)d_in[2];
  const float* Whh  = (const float*)d_in[3];
  const float* bih  = (const float*)d_in[4];
  const float* bhh  = (const float*)d_in[5];
  const float* w1h  = (const float*)d_in[6];
  const float* w2h  = (const float*)d_in[7];
  const float* w1c  = (const float*)d_in[8];
  const float* w2c  = (const float*)d_in[9];
  const float* fcW  = (const float*)d_in[10];
  const float* fcb  = (const float*)d_in[11];
  float* out = (float*)d_out;

  char* ws = (char*)d_ws;
  float* sums = (float*)(ws + WS_SUMS);
  float* hbuf = (float*)(ws + WS_HBUF);
  float* c0   = (float*)(ws + WS_C0);
  int*   ctrs = (int*)  (ws + WS_CTRS);
  float* pp   = (float*)(ws + WS_PP);

  hipMemsetAsync(ctrs, 0, GRPS * sizeof(int), stream);  // barrier counters zeroed every call
  k_segsum<<<NB, 256, 0, stream>>>(x, lens, sums);
  k_init  <<<NB, 256, 0, stream>>>(sums, w1h, w2h, w1c, w2c, hbuf, c0);
  k_lstm  <<<NB, TPB, 0, stream>>>(x, lens, Wih, Whh, bih, bhh, c0, hbuf, pp, ctrs);
  k_out   <<<NB, 256, 0, stream>>>(pp, lens, fcW, fcb, out);
}

// Round 4
// 43842.163 us; speedup vs baseline: 1.0652x; 1.0652x over previous
//
#include <hip/hip_runtime.h>
#include <stdint.h>

#define NB    256   // batch / segments
#define CIN   128   // input channels
#define HID   256   // hidden
#define TST   256   // only first 256 timesteps matter for the output
#define NCLS  400

#define GRPS  32    // batch groups
#define MEMB  8     // blocks per group (hidden-slice members)
#define BPG   8     // batches per group
#define RPB   128   // gate-rows per block (4 gates x 32 hid)
#define HPB   32    // hidden units per block
#define TPB   512   // threads per block
#define KQ    4     // K-quarters
#define KPT   96    // weight floats per thread (384/KQ)
#define SPD   12    // s_part padded row stride (floats)
#define SGD   10    // s_gate padded row stride (floats)

// ---- workspace layout (bytes) ----
#define WS_SUMS   0u                       // 256*128*4   = 131072
#define WS_HBUF   131072u                  // 2*256*256*4 = 524288  (double-buffered h)
#define WS_C0     655360u                  // 256*256*4   = 262144
#define WS_CTRS   917504u                  // 32*4 group barrier counters
#define WS_PP     1048576u                 // 256*32*8*32*4 = 8388608 masked partial sums

__device__ __forceinline__ float sigm(float v) { return 1.0f / (1.0f + __expf(-v)); }
__device__ __forceinline__ float tanh_(float v) {
  v = fminf(fmaxf(v, -15.0f), 15.0f);
  const float e = __expf(2.0f * v);
  return (e - 1.0f) / (e + 1.0f);
}

// ---------------- segment sums (the "input_means" that are really sums) ----------------
__global__ void k_segsum(const float* __restrict__ x, const int* __restrict__ lens,
                         float* __restrict__ sums) {
  const int b = blockIdx.x, t = threadIdx.x;
  __shared__ int   s_l[NB];
  __shared__ int   s_red[256];
  __shared__ float s_f[CIN];
  s_l[t] = lens[t];
  __syncthreads();
  int part = 0;
  for (int i = t; i < b; i += 256) part += s_l[i];
  s_red[t] = part; __syncthreads();
  for (int k = 128; k > 0; k >>= 1) { if (t < k) s_red[t] += s_red[t + k]; __syncthreads(); }
  const int off = s_red[0];
  const int len = s_l[b];
  const int c = t & 127, half = t >> 7;
  float a = 0.f;
  for (int r = half; r < len; r += 2) a += x[(size_t)(off + r) * CIN + c];
  if (half) s_f[c] = a;
  __syncthreads();
  if (!half) sums[b * CIN + c] = a + s_f[c];
}

// ---------------- h0 = relu(sums@W1h^T)@W2h^T ; c0 likewise ----------------
__global__ void k_init(const float* __restrict__ sums,
                       const float* __restrict__ w1h, const float* __restrict__ w2h,
                       const float* __restrict__ w1c, const float* __restrict__ w2c,
                       float* __restrict__ hbuf, float* __restrict__ c0) {
  const int b = blockIdx.x, t = threadIdx.x;
  __shared__ float s_in[CIN], s_h[CIN], s_c[CIN];
  if (t < CIN) s_in[t] = sums[b * CIN + t];
  __syncthreads();
  {
    const int j = t & 127;
    const float* w = (t < CIN ? w1h : w1c) + j * CIN;
    float a = 0.f;
    #pragma unroll 8
    for (int k = 0; k < CIN; k++) a += s_in[k] * w[k];
    a = fmaxf(a, 0.f);
    if (t < CIN) s_h[j] = a; else s_c[j] = a;
  }
  __syncthreads();
  float ah = 0.f, ac = 0.f;
  const float* wh = w2h + t * CIN;
  const float* wc = w2c + t * CIN;
  #pragma unroll 8
  for (int k = 0; k < CIN; k++) { ah += s_h[k] * wh[k]; ac += s_c[k] * wc[k]; }
  hbuf[b * HID + t] = ah;   // buffer 0 = h_0
  c0[b * HID + t]   = ac;
}

// ---------------- persistent LSTM recurrence ----------------
// 256 blocks = 32 batch-groups (8 batches) x 8 members (32 hid = 128 gate rows).
// 512 threads: thread = (gate-row r, K-quarter kq) -> 96 weight floats in VGPRs.
// REGISTER-CAP HISTORY (the whole game so far):
//   R1: 384 w/thread, cap 256      -> spill, 10 GB scratch refetch
//   R2: 192 w/thread, cap 256      -> still ~150 spilled, 10 GB refetch
//   R3: 96 w/thread,  bounds(512,2)-> cap dropped to 128! -> in-loop spill, 120 GB
//   R4: 96 w/thread,  bounds(512,1)-> cap 256, need ~150 -> expect NO spill
__launch_bounds__(TPB, 1)
__global__ void k_lstm(const float* __restrict__ x, const int* __restrict__ lens,
                       const float* __restrict__ Wih, const float* __restrict__ Whh,
                       const float* __restrict__ bih, const float* __restrict__ bhh,
                       const float* __restrict__ c0,
                       float* __restrict__ hbuf, float* __restrict__ pp,
                       int* __restrict__ ctrs) {
  const int p    = blockIdx.x;
  const int m    = p >> 5;            // member 0..7 (hidden slice)
  const int grp  = p & 31;            // batch group 0..31 (members at stride 32 -> same XCD)
  const int bat0 = grp * BPG;
  const int hid0 = m * HPB;

  const int t  = threadIdx.x;
  const int r  = t & 127;             // local gate-row 0..127
  const int kq = t >> 7;              // K-quarter 0..3 (wave-uniform)
  const int gidx = r >> 5, j = r & 31;
  const int row = gidx * HID + hid0 + j;   // global gate row 0..1023

  const int j2 = t & 31, b2 = (t >> 5) & 7;     // update role (t<256)
  const int ch = t & 127, bp0 = (t >> 7) * 2;   // x staging role (2 batches each)

  __shared__ float s_hx[(CIN + HID) * BPG];     // [384 k][8 b] = 12 KB
  __shared__ float s_part[KQ * RPB * SPD];      // 24 KB quarter partials (padded)
  __shared__ float s_gate[RPB * SGD];           // 5 KB (padded)
  __shared__ float s_red[256];
  __shared__ int   s_lens[NB];
  __shared__ int   s_off[BPG], s_len[BPG];

  if (t < NB) s_lens[t] = lens[t];
  __syncthreads();
  if (t < BPG) {
    int off = 0;
    for (int k = 0; k < bat0 + t; k++) off += s_lens[k];
    s_off[t] = off;
    s_len[t] = s_lens[bat0 + t];
  }
  __syncthreads();

  // ---- persistent weights: 96 fp32 in VGPRs (static indices after unroll) ----
  float w[KPT];
  {
    const int k0 = kq * KPT;
    #pragma unroll
    for (int q = 0; q < KPT / 4; q++) {
      const int k = k0 + q * 4;
      float4 v;
      if (k < CIN) v = *(const float4*)(Wih + (size_t)row * CIN + k);
      else         v = *(const float4*)(Whh + (size_t)row * HID + (k - CIN));
      w[q*4+0] = v.x; w[q*4+1] = v.y; w[q*4+2] = v.z; w[q*4+3] = v.w;
    }
  }
  const float bias = (kq == 0) ? (bih[row] + bhh[row]) : 0.f;

  float c_reg = (t < 256) ? c0[(size_t)(bat0 + b2) * HID + hid0 + j2] : 0.f;

  float xp0, xp1;
  auto prefx = [&](int s) {
    xp0 = (s < s_len[bp0 + 0]) ? x[(size_t)(s_off[bp0 + 0] + s) * CIN + ch] : 0.f;
    xp1 = (s < s_len[bp0 + 1]) ? x[(size_t)(s_off[bp0 + 1] + s) * CIN + ch] : 0.f;
  };
  auto stage = [&](int s) {
    *(float2*)&s_hx[ch * BPG + bp0] = make_float2(xp0, xp1);
    const int k = t & 255, bq = t >> 8;          // h staging: (hidden k, batch-quad)
    const float* hb = hbuf + (size_t)(s & 1) * NB * HID + k;
    float4 hv;
    hv.x = hb[(size_t)(bat0 + bq * 4 + 0) * HID];
    hv.y = hb[(size_t)(bat0 + bq * 4 + 1) * HID];
    hv.z = hb[(size_t)(bat0 + bq * 4 + 2) * HID];
    hv.w = hb[(size_t)(bat0 + bq * 4 + 3) * HID];
    *(float4*)&s_hx[(CIN + k) * BPG + bq * 4] = hv;
  };

  prefx(0);
  stage(0);
  __syncthreads();

  for (int s = 0; s < TST; s++) {
    // ---- gate quarter-partials: 96 K x 8 batches, hx rows are wave-uniform broadcasts ----
    float a0 = bias, a1 = bias, a2 = bias, a3 = bias;
    float a4 = bias, a5 = bias, a6 = bias, a7 = bias;
    const float4* hx4 = (const float4*)s_hx + (size_t)kq * KPT * 2;
    #pragma unroll
    for (int k = 0; k < KPT; k++) {
      const float4 lo = hx4[2 * k + 0];
      const float4 hi = hx4[2 * k + 1];
      const float ww = w[k];
      a0 = fmaf(ww, lo.x, a0); a1 = fmaf(ww, lo.y, a1);
      a2 = fmaf(ww, lo.z, a2); a3 = fmaf(ww, lo.w, a3);
      a4 = fmaf(ww, hi.x, a4); a5 = fmaf(ww, hi.y, a5);
      a6 = fmaf(ww, hi.z, a6); a7 = fmaf(ww, hi.w, a7);
    }
    if (s < TST - 1) prefx(s + 1);   // x loads drain during reduce/update/barrier

    {
      float* sp = s_part + (size_t)(kq * RPB + r) * SPD;
      *(float4*)(sp + 0) = make_float4(a0, a1, a2, a3);
      *(float4*)(sp + 4) = make_float4(a4, a5, a6, a7);
    }
    __syncthreads();

    // ---- quarter reduction: thread = (row rr, batch-pair bh) ----
    {
      const int rr = t & 127, bh = t >> 7;
      float g0 = 0.f, g1 = 0.f;
      #pragma unroll
      for (int q = 0; q < KQ; q++) {
        const float* sp = s_part + (size_t)(q * RPB + rr) * SPD + bh * 2;
        g0 += sp[0]; g1 += sp[1];
      }
      *(float2*)&s_gate[rr * SGD + bh * 2] = make_float2(g0, g1);
    }
    __syncthreads();

    // ---- LSTM update for (hidden j2, batch b2): threads 0..255 ----
    if (t < 256) {
      const float vi = s_gate[(0 * HPB + j2) * SGD + b2];
      const float vf = s_gate[(1 * HPB + j2) * SGD + b2];
      const float vg = s_gate[(2 * HPB + j2) * SGD + b2];
      const float vo = s_gate[(3 * HPB + j2) * SGD + b2];
      c_reg = fmaf(sigm(vf), c_reg, sigm(vi) * tanh_(vg));
      const float h = sigm(vo) * tanh_(c_reg);
      hbuf[(size_t)((s + 1) & 1) * NB * HID + (size_t)(bat0 + b2) * HID + hid0 + j2] = h;
      s_red[b2 * HPB + j2] = (bat0 + b2 < s_lens[s]) ? h : 0.f;
    }
    __syncthreads();

    // masked partial for output row s (overlaps barrier spin below)
    if (t >= 256 && t < 256 + HPB) {
      const int jl = t - 256;
      float ps = 0.f;
      #pragma unroll
      for (int b = 0; b < BPG; b++) ps += s_red[b * HPB + jl];
      pp[(((size_t)s * GRPS + grp) * MEMB + m) * HPB + jl] = ps;
    }

    if (s == TST - 1) break;

    // ---- 8-block group barrier: release arrive, relaxed spin + sleep, one acquire ----
    if (t == 0) {
      __hip_atomic_fetch_add(ctrs + grp, 1, __ATOMIC_RELEASE, __HIP_MEMORY_SCOPE_AGENT);
      const int target = MEMB * (s + 1);
      while (__hip_atomic_load(ctrs + grp, __ATOMIC_RELAXED, __HIP_MEMORY_SCOPE_AGENT) < target)
        __builtin_amdgcn_s_sleep(2);
      (void)__hip_atomic_load(ctrs + grp, __ATOMIC_ACQUIRE, __HIP_MEMORY_SCOPE_AGENT);
    }
    __syncthreads();
    stage(s + 1);
    __syncthreads();
  }
}

// ---------------- masked batch-mean + FC ----------------
__global__ void k_out(const float* __restrict__ pp, const int* __restrict__ lens,
                      const float* __restrict__ fcW, const float* __restrict__ fcb,
                      float* __restrict__ out) {
  const int i = blockIdx.x, t = threadIdx.x;
  __shared__ float s_fc[HID];
  const int cnt = min(lens[i], NB);
  const int m = t >> 5, jl = t & 31;             // hid = t
  float a = 0.f;
  const float* base = pp + ((size_t)i * GRPS * MEMB + m) * HPB + jl;
  #pragma unroll 4
  for (int g = 0; g < GRPS; g++) a += base[(size_t)g * MEMB * HPB];
  s_fc[t] = a / (float)cnt;
  __syncthreads();
  for (int n = t; n < NCLS; n += 256) {
    float acc = fcb[n];
    const float4* w4 = (const float4*)(fcW + (size_t)n * HID);
    #pragma unroll 8
    for (int k4 = 0; k4 < HID / 4; k4++) {
      const float4 w = w4[k4];
      acc = fmaf(s_fc[4*k4+0], w.x, acc);
      acc = fmaf(s_fc[4*k4+1], w.y, acc);
      acc = fmaf(s_fc[4*k4+2], w.z, acc);
      acc = fmaf(s_fc[4*k4+3], w.w, acc);
    }
    out[(size_t)i * NCLS + n] = acc;
  }
}

extern "C" void kernel_launch(void* const* d_in, const int* in_sizes, int n_in,
                              void* d_out, int out_size, void* d_ws, size_t ws_size,
                              hipStream_t stream) {
  const float* x    = (const float*)d_in[0];
  const int*   lens = (const int*)  d_in[1];
  const float* Wih  = (const float*)d_in[2];
  const float* Whh  = (const float*)d_in[3];
  const float* bih  = (const float*)d_in[4];
  const float* bhh  = (const float*)d_in[5];
  const float* w1h  = (const float*)d_in[6];
  const float* w2h  = (const float*)d_in[7];
  const float* w1c  = (const float*)d_in[8];
  const float* w2c  = (const float*)d_in[9];
  const float* fcW  = (const float*)d_in[10];
  const float* fcb  = (const float*)d_in[11];
  float* out = (float*)d_out;

  char* ws = (char*)d_ws;
  float* sums = (float*)(ws + WS_SUMS);
  float* hbuf = (float*)(ws + WS_HBUF);
  float* c0   = (float*)(ws + WS_C0);
  int*   ctrs = (int*)  (ws + WS_CTRS);
  float* pp   = (float*)(ws + WS_PP);

  hipMemsetAsync(ctrs, 0, GRPS * sizeof(int), stream);  // barrier counters zeroed every call
  k_segsum<<<NB, 256, 0, stream>>>(x, lens, sums);
  k_init  <<<NB, 256, 0, stream>>>(sums, w1h, w2h, w1c, w2c, hbuf, c0);
  k_lstm  <<<NB, TPB, 0, stream>>>(x, lens, Wih, Whh, bih, bhh, c0, hbuf, pp, ctrs);
  k_out   <<<NB, 256, 0, stream>>>(pp, lens, fcW, fcb, out);
}